// Round 1
// baseline (704.230 us; speedup 1.0000x reference)
//
#include <hip/hip_runtime.h>

// EntNet: B=32, S=256, L=64, D=100, M=20
// d_in: batch[B,S,L,D] f32, enc_mult[L,D], keys[M,D], U[D,D], V[D,D], W[D,D], prelu_a[1]
// d_out: mem_final [B,M,D] f32 (64000 floats)
//
// Decomposition:
//  K1: enc[b,t,:] = sum_l batch[b,t,l,:]*enc_mult[l,:]  and  sWp[b,t,e] = sum_d enc[b,t,d]*W[e,d]
//  K2: 640 independent chains (b,m); per step:
//      gate = sigmoid(s.mem + s.keys_m)   (fused into one double reduction)
//      cand = prelu(U.mem + keysV_m + sWp_row)
//      mem  = normalize(mem + cand*gate)

__global__ __launch_bounds__(256) void encode_project(
    const float* __restrict__ batch,
    const float* __restrict__ encm,
    const float* __restrict__ W,
    float* __restrict__ enc,
    float* __restrict__ sWp)
{
    __shared__ float4 part[200];   // [8][25]
    __shared__ float  encL[100];
    const int t = threadIdx.x;
    const int c = t % 25;
    const int g = t / 25;          // active for g<8 (200 threads)
    const float4* b4 = (const float4*)batch;
    const float4* e4 = (const float4*)encm;
    const float4* W4 = (const float4*)W;

    const int row0 = blockIdx.x * 8;
    for (int r = 0; r < 8; ++r) {
        const int row = row0 + r;
        const size_t base = (size_t)row * 1600;   // 64*25 float4 per row
        if (g < 8) {
            float4 acc = {0.f, 0.f, 0.f, 0.f};
            #pragma unroll
            for (int j = 0; j < 8; ++j) {
                const int l = g + 8 * j;
                float4 x  = b4[base + (size_t)l * 25 + c];
                float4 mu = e4[l * 25 + c];
                acc.x += x.x * mu.x;
                acc.y += x.y * mu.y;
                acc.z += x.z * mu.z;
                acc.w += x.w * mu.w;
            }
            part[g * 25 + c] = acc;
        }
        __syncthreads();
        if (t < 25) {
            float4 s = {0.f, 0.f, 0.f, 0.f};
            #pragma unroll
            for (int gg = 0; gg < 8; ++gg) {
                float4 p = part[gg * 25 + t];
                s.x += p.x; s.y += p.y; s.z += p.z; s.w += p.w;
            }
            ((float4*)encL)[t] = s;
            ((float4*)enc)[(size_t)row * 25 + t] = s;
        }
        __syncthreads();
        if (t < 100) {
            float acc = 0.f;
            #pragma unroll
            for (int k = 0; k < 25; ++k) {
                float4 w = W4[t * 25 + k];
                acc += w.x * encL[4 * k] + w.y * encL[4 * k + 1]
                     + w.z * encL[4 * k + 2] + w.w * encL[4 * k + 3];
            }
            sWp[(size_t)row * 100 + t] = acc;
        }
        __syncthreads();
    }
}

__global__ __launch_bounds__(128, 2) void entnet_scan(
    const float* __restrict__ enc,    // [B*S*100]
    const float* __restrict__ sWp,    // [B*S*100]
    const float* __restrict__ keys,   // [20*100]
    const float* __restrict__ U,      // [100*100]
    const float* __restrict__ V,      // [100*100]
    const float* __restrict__ paPtr,  // [1]
    float* __restrict__ out)          // [B*20*100]
{
    __shared__ float memL[100];
    __shared__ float red[8];
    const int t = threadIdx.x;
    const int wave = t >> 6;
    const int b = blockIdx.x / 20;
    const int m = blockIdx.x % 20;
    const float pa = paPtr[0];
    const int e = (t < 100) ? t : 0;

    // U row e -> registers (fully unrolled, stays in VGPRs)
    float Ureg[100];
    {
        const float4* U4 = (const float4*)(U + e * 100);
        #pragma unroll
        for (int k = 0; k < 25; ++k) {
            float4 u = U4[k];
            Ureg[4 * k]     = u.x;
            Ureg[4 * k + 1] = u.y;
            Ureg[4 * k + 2] = u.z;
            Ureg[4 * k + 3] = u.w;
        }
    }
    // keysV[m][e] = sum_d keys[m][d] * V[e][d]
    float kV = 0.f;
    {
        const float* km = keys + m * 100;
        const float* Ve = V + e * 100;
        #pragma unroll 4
        for (int d = 0; d < 100; ++d) kV += km[d] * Ve[d];
    }
    const float kKey = keys[m * 100 + e];  // keys[m][e], also the mem init
    float mem_e = kKey;
    if (t < 100) memL[t] = mem_e;
    __syncthreads();

    const float* encRow = enc + (size_t)b * (256 * 100);
    const float* sWRow  = sWp + (size_t)b * (256 * 100);

    for (int step = 0; step < 256; ++step) {
        float sv = 0.f, swv = 0.f;
        if (t < 100) {
            sv  = encRow[step * 100 + t];
            swv = sWRow[step * 100 + t];
        }
        // fused double reduction: p1 = s.mem, p2 = s.keys_m
        float p1 = sv * mem_e;
        float p2 = sv * kKey;
        #pragma unroll
        for (int off = 1; off < 64; off <<= 1) {
            p1 += __shfl_xor(p1, off, 64);
            p2 += __shfl_xor(p2, off, 64);
        }
        if ((t & 63) == 0) { red[wave * 2] = p1; red[wave * 2 + 1] = p2; }

        // matvec U.mem while reduction settles (memL stable until after B2)
        float acc = 0.f;
        const float4* m4 = (const float4*)memL;
        #pragma unroll
        for (int k = 0; k < 25; ++k) {
            float4 v = m4[k];
            acc += Ureg[4 * k] * v.x + Ureg[4 * k + 1] * v.y
                 + Ureg[4 * k + 2] * v.z + Ureg[4 * k + 3] * v.w;
        }
        __syncthreads();                       // B1: red[0..3] visible
        const float mg = red[0] + red[2];
        const float kg = red[1] + red[3];
        const float gate = 1.f / (1.f + __expf(-(mg + kg)));
        const float x = acc + kV + swv;
        const float cand = (x >= 0.f) ? x : pa * x;
        const float nm = mem_e + cand * gate;
        float q = (t < 100) ? nm * nm : 0.f;
        #pragma unroll
        for (int off = 1; off < 64; off <<= 1) q += __shfl_xor(q, off, 64);
        if ((t & 63) == 0) red[4 + wave] = q;
        __syncthreads();                       // B2: red[4..5] visible; matvec reads done
        const float rn = rsqrtf(red[4] + red[5]);
        mem_e = nm * rn;
        if (t < 100) memL[t] = mem_e;
        __syncthreads();                       // B3: memL updated for next step
    }
    if (t < 100) out[((size_t)b * 20 + m) * 100 + t] = mem_e;
}

extern "C" void kernel_launch(void* const* d_in, const int* in_sizes, int n_in,
                              void* d_out, int out_size, void* d_ws, size_t ws_size,
                              hipStream_t stream) {
    const float* batch = (const float*)d_in[0];
    const float* encm  = (const float*)d_in[1];
    const float* keys  = (const float*)d_in[2];
    const float* U     = (const float*)d_in[3];
    const float* V     = (const float*)d_in[4];
    const float* W     = (const float*)d_in[5];
    const float* pa    = (const float*)d_in[6];
    float* out = (float*)d_out;

    float* enc = (float*)d_ws;          // 32*256*100 = 819200 floats
    float* sWp = enc + 819200;          // 819200 floats  (total 6.55 MB of ws)

    encode_project<<<1024, 256, 0, stream>>>(batch, encm, W, enc, sWp);
    entnet_scan<<<640, 128, 0, stream>>>(enc, sWp, keys, U, V, pa, out);
}

// Round 3
// 519.530 us; speedup vs baseline: 1.3555x; 1.3555x over previous
//
#include <hip/hip_runtime.h>

// EntNet: B=32, S=256, L=64, D=100, M=20
// K1 encode_k : enc[r,:] = sum_l batch[r,l,:]*encm[l,:]  (r = b*256+t), pure streaming, no barriers
// K2 project_k: sWp[r,e] = sum_d enc[r,d]*W[e,d]
// K3 entnet_scan: 640 independent chains (b,m), ONE WAVE per chain, zero barriers.
//   Per lane: rows e0=lane, e1=64+lane (lane<36) of U live in VGPRs as packed float2.
//   Per step: matvec from LDS-broadcast mem; cand=prelu(U.mem+kV+sW);
//   5-way fused DPP wave reduction (||mem||^2, s.mem, s.keys, mem.cand, cand.cand);
//   gate=sigmoid; ||mem_new||^2 = p0+2g*p3+g^2*p4 (no second reduction).

typedef float v2f __attribute__((ext_vector_type(2)));

__global__ __launch_bounds__(256) void encode_k(
    const float* __restrict__ batch,
    const float* __restrict__ encm,
    float* __restrict__ enc)
{
    const int tid = blockIdx.x * 256 + threadIdx.x;   // 800 blocks -> 204800 = 8192*25
    const int r = tid / 25;
    const int c = tid % 25;
    const float4* b4 = (const float4*)batch + (size_t)r * 1600 + c;
    const float4* e4 = (const float4*)encm + c;
    float4 acc = {0.f, 0.f, 0.f, 0.f};
    #pragma unroll 8
    for (int l = 0; l < 64; ++l) {
        float4 x  = b4[l * 25];
        float4 mu = e4[l * 25];
        acc.x += x.x * mu.x;
        acc.y += x.y * mu.y;
        acc.z += x.z * mu.z;
        acc.w += x.w * mu.w;
    }
    ((float4*)enc)[(size_t)r * 25 + c] = acc;
}

__global__ __launch_bounds__(128) void project_k(
    const float* __restrict__ enc,
    const float* __restrict__ W,
    float* __restrict__ sWp)
{
    const int t = threadIdx.x;
    if (t >= 100) return;
    const int row0 = blockIdx.x * 4;                  // 2048 blocks -> 8192 rows
    const float4* w4 = (const float4*)(W + t * 100);
    const float4* e0 = (const float4*)(enc + (size_t)row0 * 100);
    const float4* e1 = e0 + 25;
    const float4* e2 = e0 + 50;
    const float4* e3 = e0 + 75;
    float a0 = 0.f, a1 = 0.f, a2 = 0.f, a3 = 0.f;
    #pragma unroll
    for (int k = 0; k < 25; ++k) {
        float4 w = w4[k];
        float4 s0 = e0[k], s1 = e1[k], s2 = e2[k], s3 = e3[k];
        a0 += w.x * s0.x + w.y * s0.y + w.z * s0.z + w.w * s0.w;
        a1 += w.x * s1.x + w.y * s1.y + w.z * s1.z + w.w * s1.w;
        a2 += w.x * s2.x + w.y * s2.y + w.z * s2.z + w.w * s2.w;
        a3 += w.x * s3.x + w.y * s3.y + w.z * s3.z + w.w * s3.w;
    }
    sWp[(size_t)row0 * 100 + t]       = a0;
    sWp[(size_t)(row0 + 1) * 100 + t] = a1;
    sWp[(size_t)(row0 + 2) * 100 + t] = a2;
    sWp[(size_t)(row0 + 3) * 100 + t] = a3;
}

template <int CTRL>
__device__ __forceinline__ float dpp_add_f(float x) {
    int s = __builtin_amdgcn_update_dpp(0, __float_as_int(x), CTRL, 0xF, 0xF, true);
    return x + __int_as_float(s);
}
__device__ __forceinline__ float lane63(float x) {
    return __int_as_float(__builtin_amdgcn_readlane(__float_as_int(x), 63));
}

__global__ __launch_bounds__(64, 1) void entnet_scan(
    const float* __restrict__ enc,    // [8192*100]
    const float* __restrict__ sWp,    // [8192*100]
    const float* __restrict__ keys,   // [20*100]
    const float* __restrict__ U,      // [100*100]
    const float* __restrict__ V,      // [100*100]
    const float* __restrict__ paPtr,
    float* __restrict__ out)          // [32*20*100]
{
    __shared__ float memL[100];
    const int lane = threadIdx.x;
    const int b = blockIdx.x / 20;
    const int m = blockIdx.x % 20;
    const bool hi = (lane < 36);
    const float h = hi ? 1.f : 0.f;
    const int e0 = lane;
    const int e1 = hi ? (64 + lane) : 99;   // clamped, always in-row
    const float pa = paPtr[0];

    // U rows e0,e1 -> 100 packed float2 in VGPRs (~200 regs; launch_bounds(64,1) allows 512)
    v2f Upk[100];
    {
        const float4* u0 = (const float4*)(U + e0 * 100);
        const float4* u1 = (const float4*)(U + e1 * 100);
        #pragma unroll
        for (int k = 0; k < 25; ++k) {
            float4 a = u0[k], c = u1[k];
            Upk[4 * k + 0] = (v2f){a.x, c.x};
            Upk[4 * k + 1] = (v2f){a.y, c.y};
            Upk[4 * k + 2] = (v2f){a.z, c.z};
            Upk[4 * k + 3] = (v2f){a.w, c.w};
        }
    }
    // keysV[m][e] for e0,e1
    v2f kV = (v2f){0.f, 0.f};
    {
        const float4* km = (const float4*)(keys + m * 100);
        const float4* v0 = (const float4*)(V + e0 * 100);
        const float4* v1 = (const float4*)(V + e1 * 100);
        #pragma unroll
        for (int k = 0; k < 25; ++k) {
            float4 kk = km[k], a = v0[k], c = v1[k];
            kV.x += a.x * kk.x + a.y * kk.y + a.z * kk.z + a.w * kk.w;
            kV.y += c.x * kk.x + c.y * kk.y + c.z * kk.z + c.w * kk.w;
        }
    }
    const float k0 = keys[m * 100 + e0];
    const float k1 = h * keys[m * 100 + e1];
    float mem0 = k0, mem1 = k1;
    memL[e0] = mem0;
    if (hi) memL[e1] = mem1;
    __asm__ __volatile__("" ::: "memory");   // compiler fence; single-wave DS is in-order

    const float* encRow = enc + (size_t)b * 25600;
    const float* sWRow  = sWp + (size_t)b * 25600;

    float sv0 = encRow[e0], sv1 = encRow[e1];
    float sw0 = sWRow[e0],  sw1 = sWRow[e1];

    for (int step = 0; step < 256; ++step) {
        // prefetch next step's sentence data (L2-hot) under the matvec
        const int nxt = (step < 255 ? step + 1 : 255) * 100;
        const float nsv0 = encRow[nxt + e0], nsv1 = encRow[nxt + e1];
        const float nsw0 = sWRow[nxt + e0], nsw1 = sWRow[nxt + e1];

        // matvec: acc = U[e0/e1,:] . mem  (mem via LDS same-address broadcast reads)
        v2f acc = (v2f){0.f, 0.f};
        const float4* m4 = (const float4*)memL;
        #pragma unroll
        for (int k = 0; k < 25; ++k) {
            float4 v = m4[k];
            acc += Upk[4 * k + 0] * v.x;
            acc += Upk[4 * k + 1] * v.y;
            acc += Upk[4 * k + 2] * v.z;
            acc += Upk[4 * k + 3] * v.w;
        }
        float c0 = acc.x + kV.x + sw0;
        float c1 = acc.y + kV.y + sw1;
        c0 = (c0 >= 0.f) ? c0 : pa * c0;     // prelu
        c1 = (c1 >= 0.f) ? c1 : pa * c1;

        // five fused partials
        float p0 = mem0 * mem0 + mem1 * mem1;          // ||mem||^2
        float p1 = sv0 * mem0 + sv1 * mem1;            // s.mem
        float p2 = sv0 * k0 + sv1 * k1;                // s.keys_m
        float p3 = mem0 * c0 + mem1 * c1;              // mem.cand
        float p4 = c0 * c0 + h * c1 * c1;              // cand.cand

        // one interleaved 5-way DPP wave64 reduction (no barriers)
        #define RND(C) p0 = dpp_add_f<C>(p0); p1 = dpp_add_f<C>(p1); \
                       p2 = dpp_add_f<C>(p2); p3 = dpp_add_f<C>(p3); p4 = dpp_add_f<C>(p4);
        RND(0x111) RND(0x112) RND(0x114) RND(0x118) RND(0x142) RND(0x143)
        #undef RND
        const float s0 = lane63(p0);
        const float s1 = lane63(p1);
        const float s2 = lane63(p2);
        const float s3 = lane63(p3);
        const float s4 = lane63(p4);

        const float g  = 1.f / (1.f + __expf(-(s1 + s2)));
        const float n2 = s0 + 2.f * g * s3 + g * g * s4;   // ||mem + g*cand||^2
        const float rn = rsqrtf(n2);
        mem0 = (mem0 + g * c0) * rn;
        mem1 = h * (mem1 + g * c1) * rn;
        memL[e0] = mem0;
        if (hi) memL[e1] = mem1;
        __asm__ __volatile__("" ::: "memory");

        sv0 = nsv0; sv1 = nsv1; sw0 = nsw0; sw1 = nsw1;
    }
    float* orow = out + (size_t)(b * 20 + m) * 100;
    orow[e0] = mem0;
    if (hi) orow[e1] = mem1;
}

extern "C" void kernel_launch(void* const* d_in, const int* in_sizes, int n_in,
                              void* d_out, int out_size, void* d_ws, size_t ws_size,
                              hipStream_t stream) {
    const float* batch = (const float*)d_in[0];
    const float* encm  = (const float*)d_in[1];
    const float* keys  = (const float*)d_in[2];
    const float* U     = (const float*)d_in[3];
    const float* V     = (const float*)d_in[4];
    const float* W     = (const float*)d_in[5];
    const float* pa    = (const float*)d_in[6];
    float* out = (float*)d_out;

    float* enc = (float*)d_ws;          // 819200 floats
    float* sWp = enc + 819200;          // 819200 floats

    encode_k<<<800, 256, 0, stream>>>(batch, encm, enc);
    project_k<<<2048, 128, 0, stream>>>(enc, W, sWp);
    entnet_scan<<<640, 64, 0, stream>>>(enc, sWp, keys, U, V, pa, out);
}